// Round 8
// baseline (649.437 us; speedup 1.0000x reference)
//
#include <hip/hip_runtime.h>
#include <hip/hip_bf16.h>
#include <stdint.h>

typedef _Float16 half_t;
typedef __attribute__((ext_vector_type(8))) _Float16 half8;
typedef __attribute__((ext_vector_type(4))) _Float16 half4v;
typedef __attribute__((ext_vector_type(4))) float float4v;
typedef unsigned long long u64;

#define D_DIM 768
#define K_CENT 1024
#define M_TOTAL 65536
#define BM 256
#define BN 256
#define BK 32
#define NT 24      /* 768/32 K-tiles */
#define NTN 4      /* 1024/256 n-tiles */

#define BPLANE 16384u  /* one hi or lo B plane per chunk: 256 rows x 64 B */

/* ws layout (bytes):
   [0, 1.5MB)     Chi: pre-swizzled f16 hi centroid tiles [n_tile(4)][chunk(24)][16KB]
   [1.5MB, 3MB)   Clo
   [3MB, +4KB)    c2[1024] fp32
   [3MB+8KB,+2MB) partial u64 [65536][4]                                    */
#define CLO_OFF  (NTN * NT * BPLANE)   /* 1.5 MB */
#define C2_OFF   (2u * CLO_OFF)        /* 3 MB */
#define PART_OFF (C2_OFF + 8192u)

/* LDS map (128 KB dynamic):
   A buffers @ 0 / 32768      (hi 16K | lo 16K each)
   B buffers @ 65536 / 98304  (hi 16K | lo 16K each)                        */

// XOR swizzle for 64B row stride; rows r,r+8 alias 2-way (free). ~0 conflicts
// measured R1-R7.
__device__ __forceinline__ uint32_t swz(uint32_t row, uint32_t kbyte) {
  return (row * 64u + kbyte) ^ (((row >> 1) & 3u) << 4);
}

__device__ __forceinline__ void gll16(const void* g, void* l) {
  __builtin_amdgcn_global_load_lds((const __attribute__((address_space(1))) void*)g,
                                   (__attribute__((address_space(3))) void*)l,
                                   16, 0, 0);
}

#define BAR() __builtin_amdgcn_s_barrier()

// ---------------- kernel 1: centroid split + c2 ----------------
__global__ __launch_bounds__(256) void prep_centroids(const float* __restrict__ cent,
                                                      uint8_t* __restrict__ ws) {
  const int n = blockIdx.x;          // centroid 0..1023
  const int nt = n >> 8, row = n & 255;
  float ss = 0.f;
  for (int d = threadIdx.x; d < D_DIM; d += 256) {
    float a = cent[n * D_DIM + d];
    ss += a * a;
    half_t hi = (half_t)a;
    half_t lo = (half_t)(a - (float)hi);
    int chunk = d >> 5, k = d & 31;
    uint32_t off = (uint32_t)(nt * NT + chunk) * BPLANE + swz((uint32_t)row, (uint32_t)k * 2u);
    *(half_t*)(ws + off) = hi;
    *(half_t*)(ws + CLO_OFF + off) = lo;
  }
  for (int s = 32; s > 0; s >>= 1) ss += __shfl_down(ss, s, 64);
  __shared__ float red[4];
  if ((threadIdx.x & 63) == 0) red[threadIdx.x >> 6] = ss;
  __syncthreads();
  if (threadIdx.x == 0) {
    float* c2 = (float*)(ws + C2_OFF);
    c2[n] = red[0] + red[1] + red[2] + red[3];
  }
}

// ------- kernel 2: 256x256 4-phase (1 barrier/phase) split-f16 GEMM + argmin -------
// Fragments are read ONE PHASE AHEAD of their MFMA use so LDS reads, global
// loads, A-conversion VALU and ds_writes all overlap the matrix pipe.
__global__ __launch_bounds__(512, 2) void cluster_gemm(const float* __restrict__ X,
                                                       const uint8_t* __restrict__ wsro,
                                                       u64* __restrict__ partial) {
  extern __shared__ uint8_t smem[];

  const int bid = blockIdx.x;
  const int L = (bid & 7) * 128 + (bid >> 3);   // bijective XCD swizzle
  const int m_tile = L >> 2, n_tile = L & 3;
  const int m0 = m_tile * BM;

  const int tid = threadIdx.x;
  const int lane = tid & 63, w = tid >> 6;
  const int wm = w >> 2, wn = w & 3;            // 2M x 4N waves; wave tile 128x64
  const uint32_t kb = (uint32_t)((lane >> 4) << 4);

  const float* c2p = (const float*)(wsro + C2_OFF);
  const int ncol = n_tile * 256 + wn * 64 + (lane & 15);
  float c2v[4];
#pragma unroll
  for (int n = 0; n < 4; ++n) c2v[n] = c2p[ncol + n * 16];

  float4v acc[8][4];
#pragma unroll
  for (int m = 0; m < 8; ++m)
#pragma unroll
    for (int n = 0; n < 4; ++n) acc[m][n] = (float4v){0.f, 0.f, 0.f, 0.f};

  float4v apf[4];
  half8 ah0[4], al0[4], ah1[4], al1[4], bh0[2], bl0[2], bh1[2], bl1[2];

#define A_LOAD(T1) { const int d0 = (T1) * BK;                                        \
  _Pragma("unroll") for (int i = 0; i < 4; ++i) {                                     \
    int f = tid + i * 512; int row = f >> 3, c4 = f & 7;                              \
    apf[i] = *(const float4v*)(X + (size_t)(m0 + row) * D_DIM + d0 + c4 * 4); } }

#define A_WRITE(DB) { _Pragma("unroll") for (int i = 0; i < 4; ++i) {                 \
    int f = tid + i * 512; int row = f >> 3, c4 = f & 7;                              \
    half4v hi, lo;                                                                    \
    _Pragma("unroll") for (int j = 0; j < 4; ++j) {                                   \
      half_t h = (half_t)apf[i][j]; hi[j] = h; lo[j] = (half_t)(apf[i][j] - (float)h);} \
    uint32_t a = (DB) + swz((uint32_t)row, (uint32_t)c4 * 8u);                        \
    *(half4v*)(smem + a) = hi; *(half4v*)(smem + a + 16384u) = lo; } }

#define B_GLL_HI(T1, DB) { const uint8_t* s_ = wsro + (uint32_t)(n_tile * NT + (T1)) * BPLANE; \
    uint32_t o_ = (uint32_t)w * 2048u;                                                \
    gll16(s_ + o_ + (lane << 4), smem + (DB) + o_);                                   \
    gll16(s_ + o_ + 1024u + (lane << 4), smem + (DB) + o_ + 1024u); }

#define B_GLL_LO(T1, DB) { const uint8_t* s_ = wsro + CLO_OFF + (uint32_t)(n_tile * NT + (T1)) * BPLANE; \
    uint32_t o_ = (uint32_t)w * 2048u;                                                \
    gll16(s_ + o_ + (lane << 4), smem + (DB) + 16384u + o_);                          \
    gll16(s_ + o_ + 1024u + (lane << 4), smem + (DB) + 16384u + o_ + 1024u); }

#define READ_A(HALF, AB, AH, AL) { _Pragma("unroll") for (int m = 0; m < 4; ++m) {    \
    uint32_t a = (AB) + swz((uint32_t)(wm * 128 + (HALF) + m * 16 + (lane & 15)), kb); \
    AH[m] = *(const half8*)(smem + a); AL[m] = *(const half8*)(smem + a + 16384u); } }

#define READ_B(NH, BB, BH, BL) { _Pragma("unroll") for (int n = 0; n < 2; ++n) {      \
    uint32_t a = (BB) + swz((uint32_t)(wn * 64 + ((NH) * 2 + n) * 16 + (lane & 15)), kb); \
    BH[n] = *(const half8*)(smem + a); BL[n] = *(const half8*)(smem + a + 16384u); } }

#define MFMA_Q(MB, NB, AH, AL, BH, BL) { __builtin_amdgcn_s_setprio(1);               \
  _Pragma("unroll") for (int m = 0; m < 4; ++m)                                       \
  _Pragma("unroll") for (int n = 0; n < 2; ++n) {                                     \
    float4v* A_ = &acc[(MB) + m][(NB) + n];                                           \
    *A_ = __builtin_amdgcn_mfma_f32_16x16x32_f16(AH[m], BH[n], *A_, 0, 0, 0);         \
    *A_ = __builtin_amdgcn_mfma_f32_16x16x32_f16(AH[m], BL[n], *A_, 0, 0, 0);         \
    *A_ = __builtin_amdgcn_mfma_f32_16x16x32_f16(AL[m], BH[n], *A_, 0, 0, 0); }       \
  __builtin_amdgcn_s_setprio(0); }

  uint32_t Ab = 0u, Bb = 65536u;

  // ---- prologue: stage tile 0 into buffer 0 ----
  A_LOAD(0);
  B_GLL_HI(0, Bb); B_GLL_LO(0, Bb);
  A_WRITE(Ab);                       // compiler waits vmcnt for apf (glls stay)
  asm volatile("s_waitcnt vmcnt(0) lgkmcnt(0)" ::: "memory");
  BAR();
  READ_A(0, Ab, ah0, al0);           // 8 reads for half0
  READ_B(0, Bb, bh0, bl0);           // 4 reads for n-pair0

  for (int t = 0; t < NT; ++t) {
    const uint32_t AbN = Ab ^ 32768u, BbN = Bb ^ 32768u;
    const bool st = (t + 1 < NT);
    // P1: issue A(t+1)->regs ; read b-pair1 ; MFMA Q(0,0)
    if (st) { A_LOAD(t + 1); }
    READ_B(1, Bb, bh1, bl1);
    MFMA_Q(0, 0, ah0, al0, bh0, bl0);
    BAR();
    // P2: issue B(t+1) glls ; read A-half1 ; MFMA Q(0,2)
    if (st) { B_GLL_HI(t + 1, BbN); B_GLL_LO(t + 1, BbN); }
    READ_A(64, Ab, ah1, al1);
    MFMA_Q(0, 2, ah0, al0, bh1, bl1);
    BAR();
    // P3: convert+ds_write A(t+1) ; MFMA Q(4,2)
    if (st) { A_WRITE(AbN); }
    MFMA_Q(4, 2, ah1, al1, bh1, bl1);
    BAR();
    // P4: MFMA Q(4,0) ; drain (glls 2 phases old, writes 1 phase old: ~free) ; swap
    MFMA_Q(4, 0, ah1, al1, bh0, bl0);
    asm volatile("s_waitcnt vmcnt(0) lgkmcnt(0)" ::: "memory");
    BAR();
    Ab = AbN; Bb = BbN;
    if (st) {                        // pre-read tile t+1's first fragment set
      READ_A(0, Ab, ah0, al0);
      READ_B(0, Bb, bh0, bl0);
    }
  }

  // ---- epilogue: score = c2 - 2*dot ; per-row argmin over this n-tile ----
  u64* scratch = (u64*)smem;         // safe: loop ended with BAR
  const int g = lane >> 4;
#pragma unroll
  for (int m = 0; m < 8; ++m) {
#pragma unroll
    for (int r = 0; r < 4; ++r) {
      u64 key = ~0ull;
#pragma unroll
      for (int n = 0; n < 4; ++n) {
        float s = c2v[n] - 2.0f * acc[m][n][r];
        uint32_t ub = __float_as_uint(s);
        ub ^= (uint32_t)((int32_t)ub >> 31) | 0x80000000u;   // order-preserving flip
        u64 cand = ((u64)ub << 32) | (uint32_t)(ncol + n * 16);
        key = cand < key ? cand : key;
      }
#pragma unroll
      for (int d = 1; d < 16; d <<= 1) {
        u64 o = __shfl_xor(key, d, 64);
        key = o < key ? o : key;
      }
      if ((lane & 15) == 0) {
        int row = wm * 128 + m * 16 + g * 4 + r;
        scratch[row * 4 + wn] = key;
      }
    }
  }
  __syncthreads();
  if (tid < 256) {
    u64 k = scratch[tid * 4];
#pragma unroll
    for (int j = 1; j < 4; ++j) { u64 o = scratch[tid * 4 + j]; k = o < k ? o : k; }
    partial[(size_t)(m0 + tid) * NTN + n_tile] = k;
  }
}

// ---------------- kernel 3: combine partials -> output ----------------
__global__ __launch_bounds__(256) void finalize(const u64* __restrict__ partial,
                                                const float* __restrict__ gates,
                                                const float* __restrict__ att,
                                                const int* __restrict__ ecp,
                                                float* __restrict__ out) {
  int r = blockIdx.x * 256 + threadIdx.x;
  const u64* p = partial + (size_t)r * NTN;
  u64 k = p[0];
#pragma unroll
  for (int j = 1; j < NTN; ++j) { u64 o = p[j]; k = o < k ? o : k; }
  int idx = (int)(uint32_t)k;
  out[r] = gates[r] * att[r] * ((idx == *ecp) ? 1.0f : 0.0f);
}

extern "C" void kernel_launch(void* const* d_in, const int* in_sizes, int n_in,
                              void* d_out, int out_size, void* d_ws, size_t ws_size,
                              hipStream_t stream) {
  const float* X     = (const float*)d_in[0];
  const float* gates = (const float*)d_in[1];
  const float* att   = (const float*)d_in[2];
  const float* cent  = (const float*)d_in[3];
  const int*   ec    = (const int*)d_in[4];
  uint8_t* ws = (uint8_t*)d_ws;
  float* out = (float*)d_out;
  u64* partial = (u64*)(ws + PART_OFF);

  hipFuncSetAttribute((const void*)cluster_gemm,
                      hipFuncAttributeMaxDynamicSharedMemorySize, 131072);

  prep_centroids<<<K_CENT, 256, 0, stream>>>(cent, ws);
  cluster_gemm<<<(M_TOTAL / BM) * NTN, 512, 131072, stream>>>(X, ws, partial);
  finalize<<<M_TOTAL / 256, 256, 0, stream>>>(partial, gates, att, ec, out);
}

// Round 11
// 647.903 us; speedup vs baseline: 1.0024x; 1.0024x over previous
//
#include <hip/hip_runtime.h>
#include <hip/hip_bf16.h>
#include <stdint.h>

typedef _Float16 half_t;
typedef __attribute__((ext_vector_type(8))) _Float16 half8;
typedef __attribute__((ext_vector_type(4))) _Float16 half4v;
typedef __attribute__((ext_vector_type(4))) float float4v;
typedef unsigned long long u64;

#define D_DIM 768
#define K_CENT 1024
#define M_TOTAL 65536
#define BM 256
#define BN 256
#define BK 32
#define NT 24      /* 768/32 K-tiles */
#define NTN 4      /* 1024/256 n-tiles */

#define BPLANE 16384u  /* one hi or lo B plane per chunk: 256 rows x 64 B */

/* ws layout (bytes):
   [0, 1.5MB)     Chi: pre-swizzled f16 hi centroid tiles [n_tile(4)][chunk(24)][16KB]
   [1.5MB, 3MB)   Clo
   [3MB, +4KB)    c2[1024] fp32
   [3MB+8KB,+2MB) partial u64 [65536][4]                                    */
#define CLO_OFF  (NTN * NT * BPLANE)   /* 1.5 MB */
#define C2_OFF   (2u * CLO_OFF)        /* 3 MB */
#define PART_OFF (C2_OFF + 8192u)

/* LDS map (128 KB dynamic):
   A buffers @ 0 / 32768      (hi 16K | lo 16K each)
   B buffers @ 65536 / 98304  (hi 16K | lo 16K each)                        */

// XOR swizzle for 64B row stride; rows r,r+8 alias 2-way (free). ~0 conflicts
// measured R1-R7.
__device__ __forceinline__ uint32_t swz(uint32_t row, uint32_t kbyte) {
  return (row * 64u + kbyte) ^ (((row >> 1) & 3u) << 4);
}

__device__ __forceinline__ void gll16(const void* g, void* l) {
  __builtin_amdgcn_global_load_lds((const __attribute__((address_space(1))) void*)g,
                                   (__attribute__((address_space(3))) void*)l,
                                   16, 0, 0);
}

#define BAR() __builtin_amdgcn_s_barrier()

// ---------------- kernel 1: centroid split + c2 ----------------
__global__ __launch_bounds__(256) void prep_centroids(const float* __restrict__ cent,
                                                      uint8_t* __restrict__ ws) {
  const int n = blockIdx.x;          // centroid 0..1023
  const int nt = n >> 8, row = n & 255;
  float ss = 0.f;
  for (int d = threadIdx.x; d < D_DIM; d += 256) {
    float a = cent[n * D_DIM + d];
    ss += a * a;
    half_t hi = (half_t)a;
    half_t lo = (half_t)(a - (float)hi);
    int chunk = d >> 5, k = d & 31;
    uint32_t off = (uint32_t)(nt * NT + chunk) * BPLANE + swz((uint32_t)row, (uint32_t)k * 2u);
    *(half_t*)(ws + off) = hi;
    *(half_t*)(ws + CLO_OFF + off) = lo;
  }
  for (int s = 32; s > 0; s >>= 1) ss += __shfl_down(ss, s, 64);
  __shared__ float red[4];
  if ((threadIdx.x & 63) == 0) red[threadIdx.x >> 6] = ss;
  __syncthreads();
  if (threadIdx.x == 0) {
    float* c2 = (float*)(ws + C2_OFF);
    c2[n] = red[0] + red[1] + red[2] + red[3];
  }
}

// ------- kernel 2: 256x256 4-phase (1 barrier/phase) split-f16 GEMM + argmin -------
// Fragments read ONE PHASE AHEAD of their MFMA use; LDS reads, global loads,
// A-convert VALU and ds_writes overlap the matrix pipe. launch_bounds(512,1):
// VGPR cap >=256 under either arg2 semantics (R8's (512,2) capped at 128 ->
// 40 MB scratch spill, MfmaUtil 27%). LDS (128KB) bounds occupancy, not VGPRs.
__global__ __launch_bounds__(512, 1) void cluster_gemm(const float* __restrict__ X,
                                                       const uint8_t* __restrict__ wsro,
                                                       u64* __restrict__ partial) {
  extern __shared__ uint8_t smem[];

  const int bid = blockIdx.x;
  const int L = (bid & 7) * 128 + (bid >> 3);   // bijective XCD swizzle
  const int m_tile = L >> 2, n_tile = L & 3;
  const int m0 = m_tile * BM;

  const int tid = threadIdx.x;
  const int lane = tid & 63, w = tid >> 6;
  const int wm = w >> 2, wn = w & 3;            // 2M x 4N waves; wave tile 128x64
  const uint32_t kb = (uint32_t)((lane >> 4) << 4);

  const float* c2p = (const float*)(wsro + C2_OFF);
  const int ncol = n_tile * 256 + wn * 64 + (lane & 15);
  float c2v[4];
#pragma unroll
  for (int n = 0; n < 4; ++n) c2v[n] = c2p[ncol + n * 16];

  float4v acc[8][4];
#pragma unroll
  for (int m = 0; m < 8; ++m)
#pragma unroll
    for (int n = 0; n < 4; ++n) acc[m][n] = (float4v){0.f, 0.f, 0.f, 0.f};

  float4v apf[4];
  half8 ah0[4], al0[4], ah1[4], al1[4], bh0[2], bl0[2], bh1[2], bl1[2];

#define A_LOAD(T1) { const int d0 = (T1) * BK;                                        \
  _Pragma("unroll") for (int i = 0; i < 4; ++i) {                                     \
    int f = tid + i * 512; int row = f >> 3, c4 = f & 7;                              \
    apf[i] = *(const float4v*)(X + (size_t)(m0 + row) * D_DIM + d0 + c4 * 4); } }

#define A_WRITE(DB) { _Pragma("unroll") for (int i = 0; i < 4; ++i) {                 \
    int f = tid + i * 512; int row = f >> 3, c4 = f & 7;                              \
    half4v hi, lo;                                                                    \
    _Pragma("unroll") for (int j = 0; j < 4; ++j) {                                   \
      half_t h = (half_t)apf[i][j]; hi[j] = h; lo[j] = (half_t)(apf[i][j] - (float)h);} \
    uint32_t a = (DB) + swz((uint32_t)row, (uint32_t)c4 * 8u);                        \
    *(half4v*)(smem + a) = hi; *(half4v*)(smem + a + 16384u) = lo; } }

#define B_GLL_HI(T1, DB) { const uint8_t* s_ = wsro + (uint32_t)(n_tile * NT + (T1)) * BPLANE; \
    uint32_t o_ = (uint32_t)w * 2048u;                                                \
    gll16(s_ + o_ + (lane << 4), smem + (DB) + o_);                                   \
    gll16(s_ + o_ + 1024u + (lane << 4), smem + (DB) + o_ + 1024u); }

#define B_GLL_LO(T1, DB) { const uint8_t* s_ = wsro + CLO_OFF + (uint32_t)(n_tile * NT + (T1)) * BPLANE; \
    uint32_t o_ = (uint32_t)w * 2048u;                                                \
    gll16(s_ + o_ + (lane << 4), smem + (DB) + 16384u + o_);                          \
    gll16(s_ + o_ + 1024u + (lane << 4), smem + (DB) + 16384u + o_ + 1024u); }

#define READ_A(HALF, AB, AH, AL) { _Pragma("unroll") for (int m = 0; m < 4; ++m) {    \
    uint32_t a = (AB) + swz((uint32_t)(wm * 128 + (HALF) + m * 16 + (lane & 15)), kb); \
    AH[m] = *(const half8*)(smem + a); AL[m] = *(const half8*)(smem + a + 16384u); } }

#define READ_B(NH, BB, BH, BL) { _Pragma("unroll") for (int n = 0; n < 2; ++n) {      \
    uint32_t a = (BB) + swz((uint32_t)(wn * 64 + ((NH) * 2 + n) * 16 + (lane & 15)), kb); \
    BH[n] = *(const half8*)(smem + a); BL[n] = *(const half8*)(smem + a + 16384u); } }

#define MFMA_Q(MB, NB, AH, AL, BH, BL) { __builtin_amdgcn_s_setprio(1);               \
  _Pragma("unroll") for (int m = 0; m < 4; ++m)                                       \
  _Pragma("unroll") for (int n = 0; n < 2; ++n) {                                     \
    float4v* A_ = &acc[(MB) + m][(NB) + n];                                           \
    *A_ = __builtin_amdgcn_mfma_f32_16x16x32_f16(AH[m], BH[n], *A_, 0, 0, 0);         \
    *A_ = __builtin_amdgcn_mfma_f32_16x16x32_f16(AH[m], BL[n], *A_, 0, 0, 0);         \
    *A_ = __builtin_amdgcn_mfma_f32_16x16x32_f16(AL[m], BH[n], *A_, 0, 0, 0); }       \
  __builtin_amdgcn_s_setprio(0); }

  uint32_t Ab = 0u, Bb = 65536u;

  // ---- prologue: stage tile 0 into buffer 0 ----
  A_LOAD(0);
  B_GLL_HI(0, Bb); B_GLL_LO(0, Bb);
  A_WRITE(Ab);                       // compiler waits vmcnt for apf (glls stay)
  asm volatile("s_waitcnt vmcnt(0) lgkmcnt(0)" ::: "memory");
  BAR();
  READ_A(0, Ab, ah0, al0);           // 8 reads for half0
  READ_B(0, Bb, bh0, bl0);           // 4 reads for n-pair0

  for (int t = 0; t < NT; ++t) {
    const uint32_t AbN = Ab ^ 32768u, BbN = Bb ^ 32768u;
    const bool st = (t + 1 < NT);
    // P1: issue A(t+1)->regs ; read b-pair1 ; MFMA Q(0,0)
    if (st) { A_LOAD(t + 1); }
    READ_B(1, Bb, bh1, bl1);
    MFMA_Q(0, 0, ah0, al0, bh0, bl0);
    BAR();
    // P2: issue B(t+1) glls ; read A-half1 ; MFMA Q(0,2)
    if (st) { B_GLL_HI(t + 1, BbN); B_GLL_LO(t + 1, BbN); }
    READ_A(64, Ab, ah1, al1);
    MFMA_Q(0, 2, ah0, al0, bh1, bl1);
    BAR();
    // P3: convert+ds_write A(t+1) ; MFMA Q(4,2)
    if (st) { A_WRITE(AbN); }
    MFMA_Q(4, 2, ah1, al1, bh1, bl1);
    BAR();
    // P4: MFMA Q(4,0) ; drain (glls 2 phases old, writes 1 phase old: ~free) ; swap
    MFMA_Q(4, 0, ah1, al1, bh0, bl0);
    asm volatile("s_waitcnt vmcnt(0) lgkmcnt(0)" ::: "memory");
    BAR();
    Ab = AbN; Bb = BbN;
    if (st) {                        // pre-read tile t+1's first fragment set
      READ_A(0, Ab, ah0, al0);
      READ_B(0, Bb, bh0, bl0);
    }
  }

  // ---- epilogue: score = c2 - 2*dot ; per-row argmin over this n-tile ----
  u64* scratch = (u64*)smem;         // safe: loop ended with BAR
  const int g = lane >> 4;
#pragma unroll
  for (int m = 0; m < 8; ++m) {
#pragma unroll
    for (int r = 0; r < 4; ++r) {
      u64 key = ~0ull;
#pragma unroll
      for (int n = 0; n < 4; ++n) {
        float s = c2v[n] - 2.0f * acc[m][n][r];
        uint32_t ub = __float_as_uint(s);
        ub ^= (uint32_t)((int32_t)ub >> 31) | 0x80000000u;   // order-preserving flip
        u64 cand = ((u64)ub << 32) | (uint32_t)(ncol + n * 16);
        key = cand < key ? cand : key;
      }
#pragma unroll
      for (int d = 1; d < 16; d <<= 1) {
        u64 o = __shfl_xor(key, d, 64);
        key = o < key ? o : key;
      }
      if ((lane & 15) == 0) {
        int row = wm * 128 + m * 16 + g * 4 + r;
        scratch[row * 4 + wn] = key;
      }
    }
  }
  __syncthreads();
  if (tid < 256) {
    u64 k = scratch[tid * 4];
#pragma unroll
    for (int j = 1; j < 4; ++j) { u64 o = scratch[tid * 4 + j]; k = o < k ? o : k; }
    partial[(size_t)(m0 + tid) * NTN + n_tile] = k;
  }
}

// ---------------- kernel 3: combine partials -> output ----------------
__global__ __launch_bounds__(256) void finalize(const u64* __restrict__ partial,
                                                const float* __restrict__ gates,
                                                const float* __restrict__ att,
                                                const int* __restrict__ ecp,
                                                float* __restrict__ out) {
  int r = blockIdx.x * 256 + threadIdx.x;
  const u64* p = partial + (size_t)r * NTN;
  u64 k = p[0];
#pragma unroll
  for (int j = 1; j < NTN; ++j) { u64 o = p[j]; k = o < k ? o : k; }
  int idx = (int)(uint32_t)k;
  out[r] = gates[r] * att[r] * ((idx == *ecp) ? 1.0f : 0.0f);
}

extern "C" void kernel_launch(void* const* d_in, const int* in_sizes, int n_in,
                              void* d_out, int out_size, void* d_ws, size_t ws_size,
                              hipStream_t stream) {
  const float* X     = (const float*)d_in[0];
  const float* gates = (const float*)d_in[1];
  const float* att   = (const float*)d_in[2];
  const float* cent  = (const float*)d_in[3];
  const int*   ec    = (const int*)d_in[4];
  uint8_t* ws = (uint8_t*)d_ws;
  float* out = (float*)d_out;
  u64* partial = (u64*)(ws + PART_OFF);

  hipFuncSetAttribute((const void*)cluster_gemm,
                      hipFuncAttributeMaxDynamicSharedMemorySize, 131072);

  prep_centroids<<<K_CENT, 256, 0, stream>>>(cent, ws);
  cluster_gemm<<<(M_TOTAL / BM) * NTN, 512, 131072, stream>>>(X, ws, partial);
  finalize<<<M_TOTAL / 256, 256, 0, stream>>>(partial, gates, att, ec, out);
}